// Round 14
// baseline (216.808 us; speedup 1.0000x reference)
//
#include <hip/hip_runtime.h>

#define NM 32
#define ND 256
#define NH 8
#define NFF 1024
#define NROWS 16384

typedef __attribute__((ext_vector_type(8))) short short8;
typedef __attribute__((ext_vector_type(4))) float floatx4;

__device__ __forceinline__ unsigned short f2bf(float f){
  unsigned u = __float_as_uint(f);
  u += 0x7fffu + ((u >> 16) & 1u);
  return (unsigned short)(u >> 16);
}
__device__ __forceinline__ float bf2f(unsigned short s){
  return __uint_as_float(((unsigned)s) << 16);
}

// ================= prep: weight conversions only (node cvt folded into Qb GEMM) ==
// [0,64): Wq   [64,320): W1   [320,576): W2   [576,640): Wk transpose+cvt
// [640,704): Wv   [704,768): Wo
__global__ __launch_bounds__(256) void prep_kernel(
    const float* __restrict__ Wq, unsigned short* __restrict__ wq_b,
    const float* __restrict__ W1, unsigned short* __restrict__ w1_b,
    const float* __restrict__ W2, unsigned short* __restrict__ w2_b,
    const float* __restrict__ Wk, unsigned short* __restrict__ wkt_b,
    const float* __restrict__ Wv, unsigned short* __restrict__ wv_b,
    const float* __restrict__ Wo, unsigned short* __restrict__ wo_b){
  __shared__ float T[32][33];
  const int b = blockIdx.x, tid = threadIdx.x;
  if (b < 576 || b >= 640){
    const float* src; unsigned short* dst; int i;
    if      (b < 64) { src = Wq; dst = wq_b; i = b*256 + tid; }
    else if (b < 320){ src = W1; dst = w1_b; i = (b-64)*256 + tid; }
    else if (b < 576){ src = W2; dst = w2_b; i = (b-320)*256 + tid; }
    else if (b < 704){ src = Wv; dst = wv_b; i = (b-640)*256 + tid; }
    else             { src = Wo; dst = wo_b; i = (b-704)*256 + tid; }
    const float4 v = ((const float4*)src)[i];
    ushort4 o; o.x=f2bf(v.x); o.y=f2bf(v.y); o.z=f2bf(v.z); o.w=f2bf(v.w);
    ((ushort4*)dst)[i] = o;
  } else {
    const int bb = b - 576, ti = bb >> 3, tj = bb & 7;
    {
      const int r = tid >> 3, c4 = (tid & 7) * 4;
      const float4 v = *(const float4*)&Wk[(ti*32 + r)*256 + tj*32 + c4];
      T[r][c4+0]=v.x; T[r][c4+1]=v.y; T[r][c4+2]=v.z; T[r][c4+3]=v.w;
    }
    __syncthreads();
    {
      const int cc = tid >> 3, r4 = (tid & 7) * 4;
      ushort4 o;
      o.x=f2bf(T[r4+0][cc]); o.y=f2bf(T[r4+1][cc]);
      o.z=f2bf(T[r4+2][cc]); o.w=f2bf(T[r4+3][cc]);
      *(ushort4*)&wkt_b[(tj*32 + cc)*256 + ti*32 + r4] = o;
    }
  }
}

// ====== gemm_qb: Qb = bf16((node_f32 @ Wq^T + bq)*scale), cvt fused in staging ===
// 64x128 tile, 4 waves (2x2 of 32x64), K=256
__global__ __launch_bounds__(256) void gemm_qb(const float* __restrict__ A,
    const unsigned short* __restrict__ W, const float* __restrict__ bias,
    unsigned short* __restrict__ out, float scale){
  __shared__ unsigned short As[64][40];
  __shared__ unsigned short Bs[128][40];
  const int tid = threadIdx.x;
  const int wid = tid >> 6, lane = tid & 63, ln = lane & 15, kh = lane >> 4;
  const int wr = (wid >> 1) * 32, wc = (wid & 1) * 64;
  const int row0 = blockIdx.x * 64, col0 = blockIdx.y * 128;
  const int ar = tid >> 2, ac = (tid & 3) * 8;
  const int br = tid >> 1, bc = (tid & 1) * 16;
  floatx4 acc[2][4] = {};
  for (int k0 = 0; k0 < 256; k0 += 32){
    __syncthreads();
    {
      const float4 a = *(const float4*)&A[(size_t)(row0+ar)*256 + k0 + ac];
      const float4 b = *(const float4*)&A[(size_t)(row0+ar)*256 + k0 + ac + 4];
      short8 v;
      v[0]=(short)f2bf(a.x); v[1]=(short)f2bf(a.y); v[2]=(short)f2bf(a.z); v[3]=(short)f2bf(a.w);
      v[4]=(short)f2bf(b.x); v[5]=(short)f2bf(b.y); v[6]=(short)f2bf(b.z); v[7]=(short)f2bf(b.w);
      *(short8*)&As[ar][ac] = v;
    }
    *(short8*)&Bs[br][bc]   = *(const short8*)&W[(size_t)(col0+br)*256 + k0 + bc];
    *(short8*)&Bs[br][bc+8] = *(const short8*)&W[(size_t)(col0+br)*256 + k0 + bc + 8];
    __syncthreads();
    short8 af[2], bf[4];
    #pragma unroll
    for (int t = 0; t < 2; ++t) af[t] = *(const short8*)&As[wr + t*16 + ln][kh*8];
    #pragma unroll
    for (int t = 0; t < 4; ++t) bf[t] = *(const short8*)&Bs[wc + t*16 + ln][kh*8];
    #pragma unroll
    for (int mt = 0; mt < 2; ++mt)
      #pragma unroll
      for (int nt = 0; nt < 4; ++nt)
        acc[mt][nt] = __builtin_amdgcn_mfma_f32_16x16x32_bf16(af[mt], bf[nt], acc[mt][nt], 0, 0, 0);
  }
  #pragma unroll
  for (int mt = 0; mt < 2; ++mt){
    #pragma unroll
    for (int nt = 0; nt < 4; ++nt){
      const int gc = col0 + wc + nt*16 + ln;
      const float bs = bias[gc];
      #pragma unroll
      for (int r = 0; r < 4; ++r){
        const int gr = row0 + wr + mt*16 + kh*4 + r;
        out[(size_t)gr*256 + gc] = f2bf((acc[mt][nt][r] + bs) * scale);
      }
    }
  }
}

// ================ gemm64: 64x128 tile, 4 waves (2x2 of 32x64) ===============
// EPI 0: relu(acc+bias)->bf16 ; EPI 1: (acc+bias)*scale->bf16
template<int EPI>
__global__ __launch_bounds__(256) void gemm64(const unsigned short* __restrict__ A,
    const unsigned short* __restrict__ W, const float* __restrict__ bias,
    unsigned short* __restrict__ out, int Nc, int K, float scale){
  __shared__ unsigned short As[64][40];
  __shared__ unsigned short Bs[128][40];
  const int tid = threadIdx.x;
  const int wid = tid >> 6, lane = tid & 63, ln = lane & 15, kh = lane >> 4;
  const int wr = (wid >> 1) * 32, wc = (wid & 1) * 64;
  const int row0 = blockIdx.x * 64, col0 = blockIdx.y * 128;
  const int ar = tid >> 2, ac = (tid & 3) * 8;
  const int br = tid >> 1, bc = (tid & 1) * 16;
  floatx4 acc[2][4] = {};
  for (int k0 = 0; k0 < K; k0 += 32){
    __syncthreads();
    *(short8*)&As[ar][ac]   = *(const short8*)&A[(size_t)(row0+ar)*K + k0 + ac];
    *(short8*)&Bs[br][bc]   = *(const short8*)&W[(size_t)(col0+br)*K + k0 + bc];
    *(short8*)&Bs[br][bc+8] = *(const short8*)&W[(size_t)(col0+br)*K + k0 + bc + 8];
    __syncthreads();
    short8 af[2], bf[4];
    #pragma unroll
    for (int t = 0; t < 2; ++t) af[t] = *(const short8*)&As[wr + t*16 + ln][kh*8];
    #pragma unroll
    for (int t = 0; t < 4; ++t) bf[t] = *(const short8*)&Bs[wc + t*16 + ln][kh*8];
    #pragma unroll
    for (int mt = 0; mt < 2; ++mt)
      #pragma unroll
      for (int nt = 0; nt < 4; ++nt)
        acc[mt][nt] = __builtin_amdgcn_mfma_f32_16x16x32_bf16(af[mt], bf[nt], acc[mt][nt], 0, 0, 0);
  }
  #pragma unroll
  for (int mt = 0; mt < 2; ++mt){
    #pragma unroll
    for (int nt = 0; nt < 4; ++nt){
      const int gc = col0 + wc + nt*16 + ln;
      const float bs = bias[gc];
      #pragma unroll
      for (int r = 0; r < 4; ++r){
        const int gr = row0 + wr + mt*16 + kh*4 + r;
        const float v = acc[mt][nt][r] + bs;
        if (EPI == 0) out[(size_t)gr*Nc + gc] = f2bf(fmaxf(v, 0.f));
        else          out[(size_t)gr*Nc + gc] = f2bf(v * scale);
      }
    }
  }
}

// ---------------- qk GEMM (per head, K=32): qk[n][h*256+e] -------------------
__global__ __launch_bounds__(256) void gemm_qk(const unsigned short* __restrict__ A,
    const unsigned short* __restrict__ Wkt, unsigned short* __restrict__ out){
  __shared__ unsigned short As[128][40];
  __shared__ unsigned short Bs[128][40];
  const int tid = threadIdx.x;
  const int wid = tid >> 6, lane = tid & 63, ln = lane & 15, kh = lane >> 4;
  const int wr = (wid >> 1) * 64, wc = (wid & 1) * 64;
  const int row0 = blockIdx.x * 128, col0 = blockIdx.y * 128, h = blockIdx.z;
  #pragma unroll
  for (int it = 0; it < 2; ++it){
    const int flat = it*256 + tid;
    const int r = flat >> 2, c = flat & 3;
    *(short8*)&As[r][c*8] = *(const short8*)&A[(size_t)(row0+r)*256 + h*32 + c*8];
    *(short8*)&Bs[r][c*8] = *(const short8*)&Wkt[(size_t)(col0+r)*256 + h*32 + c*8];
  }
  __syncthreads();
  short8 af[4], bf[4];
  #pragma unroll
  for (int t = 0; t < 4; ++t) af[t] = *(const short8*)&As[wr + t*16 + ln][kh*8];
  #pragma unroll
  for (int t = 0; t < 4; ++t) bf[t] = *(const short8*)&Bs[wc + t*16 + ln][kh*8];
  floatx4 acc[4][4] = {};
  #pragma unroll
  for (int mt = 0; mt < 4; ++mt)
    #pragma unroll
    for (int nt = 0; nt < 4; ++nt)
      acc[mt][nt] = __builtin_amdgcn_mfma_f32_16x16x32_bf16(af[mt], bf[nt], acc[mt][nt], 0, 0, 0);
  #pragma unroll
  for (int mt = 0; mt < 4; ++mt)
    #pragma unroll
    for (int nt = 0; nt < 4; ++nt)
      #pragma unroll
      for (int r = 0; r < 4; ++r)
        out[(size_t)(row0 + wr + mt*16 + kh*4 + r)*2048 + h*256 + col0 + wc + nt*16 + ln]
            = f2bf(acc[mt][nt][r]);
}

// ====== gemm_vbar: vbar[n][h*32+c] = pbar[n][h-slice]@Wv_row + bv ===========
// grid (NROWS/128, 8 heads); 4 waves x (32 rows x 32 cols); K=256
__global__ __launch_bounds__(256) void gemm_vbar(const unsigned short* __restrict__ A,
    const unsigned short* __restrict__ Wv, const float* __restrict__ bv,
    unsigned short* __restrict__ out){
  __shared__ unsigned short As[128][40];
  __shared__ unsigned short Bs[32][40];
  const int tid = threadIdx.x, wid = tid >> 6, lane = tid & 63;
  const int ln = lane & 15, kh = lane >> 4;
  const int row0 = blockIdx.x * 128, h = blockIdx.y;
  floatx4 acc[2][2] = {};
  for (int k0 = 0; k0 < 256; k0 += 32){
    __syncthreads();
    {
      const int r = tid >> 2, c = (tid & 3) * 8;
      *(short8*)&As[r][c]    = *(const short8*)&A[(size_t)(row0+r)*2048 + h*256 + k0 + c];
      *(short8*)&As[r+64][c] = *(const short8*)&A[(size_t)(row0+r+64)*2048 + h*256 + k0 + c];
    }
    if (tid < 128){
      const int r = tid >> 2, c = (tid & 3) * 8;
      *(short8*)&Bs[r][c] = *(const short8*)&Wv[(size_t)(h*32+r)*256 + k0 + c];
    }
    __syncthreads();
    short8 af[2], bf[2];
    #pragma unroll
    for (int t = 0; t < 2; ++t) af[t] = *(const short8*)&As[wid*32 + t*16 + ln][kh*8];
    #pragma unroll
    for (int t = 0; t < 2; ++t) bf[t] = *(const short8*)&Bs[t*16 + ln][kh*8];
    #pragma unroll
    for (int mt = 0; mt < 2; ++mt)
      #pragma unroll
      for (int nt = 0; nt < 2; ++nt)
        acc[mt][nt] = __builtin_amdgcn_mfma_f32_16x16x32_bf16(af[mt], bf[nt], acc[mt][nt], 0, 0, 0);
  }
  #pragma unroll
  for (int mt = 0; mt < 2; ++mt)
    #pragma unroll
    for (int nt = 0; nt < 2; ++nt){
      const int gc = h*32 + nt*16 + ln;
      const float bs = bv[gc];
      #pragma unroll
      for (int r = 0; r < 4; ++r){
        const int gr = row0 + wid*32 + mt*16 + kh*4 + r;
        out[(size_t)gr*256 + gc] = f2bf(acc[mt][nt][r] + bs);
      }
    }
}

// ===== gemm_ln: 64x256 full-width tile + fused residual + LayerNorm =========
// VAR 0: resid f32, out bf16 ; VAR 1: resid bf16, out f32
template<int VAR>
__global__ __launch_bounds__(256) void gemm_ln(const unsigned short* __restrict__ A,
    const unsigned short* __restrict__ W, const float* __restrict__ bias,
    const void* __restrict__ resid, const float* __restrict__ g,
    const float* __restrict__ be, void* __restrict__ out, int K){
  __shared__ unsigned short As[64][40];
  __shared__ unsigned short Bs[256][40];
  __shared__ float red[64][4][2];
  const int tid = threadIdx.x, wid = tid >> 6, lane = tid & 63;
  const int ln = lane & 15, kh = lane >> 4;
  const int row0 = blockIdx.x * 64;
  floatx4 acc[4][4] = {};
  for (int k0 = 0; k0 < K; k0 += 32){
    __syncthreads();
    {
      const int r = tid >> 2, c = (tid & 3) * 8;
      *(short8*)&As[r][c] = *(const short8*)&A[(size_t)(row0+r)*K + k0 + c];
    }
    {
      const int rb = tid >> 2, c = (tid & 3) * 8;
      #pragma unroll
      for (int i = 0; i < 4; ++i)
        *(short8*)&Bs[rb + i*64][c] = *(const short8*)&W[(size_t)(rb + i*64)*K + k0 + c];
    }
    __syncthreads();
    short8 af[4], bf[4];
    #pragma unroll
    for (int t = 0; t < 4; ++t) af[t] = *(const short8*)&As[t*16 + ln][kh*8];
    #pragma unroll
    for (int t = 0; t < 4; ++t) bf[t] = *(const short8*)&Bs[wid*64 + t*16 + ln][kh*8];
    #pragma unroll
    for (int mt = 0; mt < 4; ++mt)
      #pragma unroll
      for (int nt = 0; nt < 4; ++nt)
        acc[mt][nt] = __builtin_amdgcn_mfma_f32_16x16x32_bf16(af[mt], bf[nt], acc[mt][nt], 0, 0, 0);
  }
  #pragma unroll
  for (int mt = 0; mt < 4; ++mt)
    #pragma unroll
    for (int nt = 0; nt < 4; ++nt){
      const int col = wid*64 + nt*16 + ln;
      const float bs = bias[col];
      #pragma unroll
      for (int r = 0; r < 4; ++r){
        const size_t idx = (size_t)(row0 + mt*16 + kh*4 + r)*256 + col;
        const float rv = (VAR == 0) ? ((const float*)resid)[idx]
                                    : bf2f(((const unsigned short*)resid)[idx]);
        acc[mt][nt][r] += bs + rv;
      }
    }
  #pragma unroll
  for (int mt = 0; mt < 4; ++mt)
    #pragma unroll
    for (int r = 0; r < 4; ++r){
      float s = 0.f, q = 0.f;
      #pragma unroll
      for (int nt = 0; nt < 4; ++nt){ const float v = acc[mt][nt][r]; s += v; q += v*v; }
      #pragma unroll
      for (int off = 8; off; off >>= 1){
        s += __shfl_xor(s, off, 16);
        q += __shfl_xor(q, off, 16);
      }
      if (ln == 0){
        red[mt*16 + kh*4 + r][wid][0] = s;
        red[mt*16 + kh*4 + r][wid][1] = q;
      }
    }
  __syncthreads();
  float ge[4], bee[4];
  #pragma unroll
  for (int nt = 0; nt < 4; ++nt){
    const int col = wid*64 + nt*16 + ln;
    ge[nt] = g[col]; bee[nt] = be[col];
  }
  #pragma unroll
  for (int mt = 0; mt < 4; ++mt)
    #pragma unroll
    for (int r = 0; r < 4; ++r){
      const int rl = mt*16 + kh*4 + r;
      const float sum = red[rl][0][0] + red[rl][1][0] + red[rl][2][0] + red[rl][3][0];
      const float sq  = red[rl][0][1] + red[rl][1][1] + red[rl][2][1] + red[rl][3][1];
      const float mu = sum * (1.f/256.f);
      const float rs = rsqrtf(sq * (1.f/256.f) - mu*mu + 1e-5f);
      const size_t rowb = (size_t)(row0 + rl) * 256;
      #pragma unroll
      for (int nt = 0; nt < 4; ++nt){
        const int col = wid*64 + nt*16 + ln;
        const float o = (acc[mt][nt][r] - mu) * rs * ge[nt] + bee[nt];
        if (VAR == 0) ((unsigned short*)out)[rowb + col] = f2bf(o);
        else          ((float*)out)[rowb + col] = o;
      }
    }
}

// ---------------- fused attention: 1 wave = 1 node, no barriers ----------------
// Masked neighbors (P == exactly 0 after softmax) are never loaded from HBM.
__global__ __launch_bounds__(256) void attn2_kernel(const float* __restrict__ neigh,
    const int* __restrict__ mask, const unsigned short* __restrict__ qk,
    unsigned short* __restrict__ pbar){
  __shared__ unsigned short Xs[4][8192];
  __shared__ float Pl[4][32][8];
  __shared__ float Mf[4][32];
  const int tid = threadIdx.x;
  const int wid = tid >> 6, lane = tid & 63;
  const int ln = lane & 15, kh = lane >> 4;
  const size_t nid = (size_t)blockIdx.x * 4 + wid;
  unsigned short* X = Xs[wid];

  int mk = 0;
  if (lane < 32) mk = mask[nid*NM + lane];
  const unsigned long long bal = __ballot(mk != 0);
  const unsigned rowmask = (unsigned)(bal & 0xffffffffull);
  const bool any = rowmask != 0;

  const float* xg = neigh + nid * (NM*ND);
  const float4 fz = {0.f, 0.f, 0.f, 0.f};
  float4 va[16], vb[16];
  #pragma unroll
  for (int i = 0; i < 16; ++i){
    const int f8 = i*64 + lane;
    const int row = f8 >> 5;
    const bool keep = (!any) || ((rowmask >> row) & 1u);
    va[i] = fz; vb[i] = fz;
    if (keep){
      va[i] = *(const float4*)&xg[f8*8];
      vb[i] = *(const float4*)&xg[f8*8 + 4];
    }
  }
  short8 bfrag[8];
  const unsigned short* qkn = qk + nid*2048 + (size_t)(ln & 7)*256;
  #pragma unroll
  for (int kk = 0; kk < 8; ++kk) bfrag[kk] = *(const short8*)&qkn[kk*32 + kh*8];

  if (lane < 32) Mf[wid][lane] = mk ? 0.f : -1e9f;

  #pragma unroll
  for (int i = 0; i < 16; ++i){
    const int f8 = i*64 + lane;
    const int m = f8 >> 5, ec = f8 & 31;
    short8 v;
    v[0]=(short)f2bf(va[i].x); v[1]=(short)f2bf(va[i].y);
    v[2]=(short)f2bf(va[i].z); v[3]=(short)f2bf(va[i].w);
    v[4]=(short)f2bf(vb[i].x); v[5]=(short)f2bf(vb[i].y);
    v[6]=(short)f2bf(vb[i].z); v[7]=(short)f2bf(vb[i].w);
    *(short8*)&X[m*256 + ((ec ^ (m & 31)) << 3)] = v;
  }

  floatx4 acc0 = {}, acc1 = {};
  #pragma unroll
  for (int kk = 0; kk < 8; ++kk){
    const int slot = kk*4 + kh;
    const int m0 = ln, m1 = 16 + ln;
    const short8 a0 = *(const short8*)&X[m0*256 + ((slot ^ (m0 & 31)) << 3)];
    const short8 a1 = *(const short8*)&X[m1*256 + ((slot ^ (m1 & 31)) << 3)];
    acc0 = __builtin_amdgcn_mfma_f32_16x16x32_bf16(a0, bfrag[kk], acc0, 0, 0, 0);
    acc1 = __builtin_amdgcn_mfma_f32_16x16x32_bf16(a1, bfrag[kk], acc1, 0, 0, 0);
  }

  float p8[8]; float mx = -3.0e38f;
  #pragma unroll
  for (int r = 0; r < 4; ++r){
    const float s0 = acc0[r] + Mf[wid][kh*4 + r];
    const float s1 = acc1[r] + Mf[wid][16 + kh*4 + r];
    p8[r] = s0; p8[4+r] = s1;
    mx = fmaxf(mx, fmaxf(s0, s1));
  }
  mx = fmaxf(mx, __shfl_xor(mx, 16));
  mx = fmaxf(mx, __shfl_xor(mx, 32));
  float sum = 0.f;
  #pragma unroll
  for (int k = 0; k < 8; ++k){ p8[k] = __expf(p8[k] - mx); sum += p8[k]; }
  sum += __shfl_xor(sum, 16);
  sum += __shfl_xor(sum, 32);
  const float inv = 1.f / sum;
  if (ln < 8){
    #pragma unroll
    for (int r = 0; r < 4; ++r){
      Pl[wid][kh*4 + r][ln]      = p8[r]   * inv;
      Pl[wid][16 + kh*4 + r][ln] = p8[4+r] * inv;
    }
  }

  const int hh = lane >> 5, ec = lane & 31;
  float pb[4][8] = {};
  #pragma unroll 4
  for (int m = 0; m < 32; ++m){
    const short8 xv = *(const short8*)&X[m*256 + ((ec ^ (m & 31)) << 3)];
    const floatx4 pv = *(const floatx4*)&Pl[wid][m][hh*4];
    float xf[8];
    #pragma unroll
    for (int j = 0; j < 8; ++j) xf[j] = bf2f((unsigned short)xv[j]);
    #pragma unroll
    for (int r = 0; r < 4; ++r)
      #pragma unroll
      for (int j = 0; j < 8; ++j) pb[r][j] += pv[r] * xf[j];
  }
  unsigned short* dst = pbar + nid*2048 + ec*8;
  #pragma unroll
  for (int r = 0; r < 4; ++r){
    short8 o;
    #pragma unroll
    for (int j = 0; j < 8; ++j) o[j] = (short)f2bf(pb[r][j]);
    *(short8*)&dst[(hh*4 + r)*256] = o;
  }
}

// ---------------- launch ----------------
extern "C" void kernel_launch(void* const* d_in, const int* in_sizes, int n_in,
                              void* d_out, int out_size, void* d_ws, size_t ws_size,
                              hipStream_t stream){
  const float* node  = (const float*)d_in[0];
  const float* neigh = (const float*)d_in[1];
  const int*   maskp = (const int*)d_in[2];
  const float* Wq = (const float*)d_in[3];  const float* bq = (const float*)d_in[4];
  const float* Wk = (const float*)d_in[5];  /* bk dropped: softmax-invariant */
  const float* Wv = (const float*)d_in[7];  const float* bvp = (const float*)d_in[8];
  const float* Wo = (const float*)d_in[9];  const float* bo = (const float*)d_in[10];
  const float* g1 = (const float*)d_in[11]; const float* be1 = (const float*)d_in[12];
  const float* W1 = (const float*)d_in[13]; const float* b1 = (const float*)d_in[14];
  const float* W2 = (const float*)d_in[15]; const float* b2 = (const float*)d_in[16];
  const float* g2 = (const float*)d_in[17]; const float* be2 = (const float*)d_in[18];

  char* ws = (char*)d_ws;
  unsigned short* wq_b  = (unsigned short*)(ws);              // 128K
  unsigned short* w1_b  = (unsigned short*)(ws + 131072);     // 512K
  unsigned short* w2_b  = (unsigned short*)(ws + 655360);     // 512K
  unsigned short* wkt_b = (unsigned short*)(ws + 1179648);    // 128K
  unsigned short* wv_b  = (unsigned short*)(ws + 1310720);    // 128K
  unsigned short* wo_b  = (unsigned short*)(ws + 1441792);    // 128K

  const size_t MB = 1048576ull;
  char* big = ws + 4*MB;
  unsigned short* Qb     = (unsigned short*)(big);            // 8M
  unsigned short* xb     = (unsigned short*)(big + 8*MB);     // 8M
  unsigned short* qk     = (unsigned short*)(big + 16*MB);    // 64M
  unsigned short* pbar   = (unsigned short*)(big + 80*MB);    // 64M
  unsigned short* vbar   = (unsigned short*)(big + 144*MB);   // 8M
  unsigned short* hbuf   = (unsigned short*)(big + 152*MB);   // 32M
  const size_t need = 4*MB + 184*MB;
  if (ws_size < need) return;

  // 1. weight prep (node cvt folded into gemm_qb)
  prep_kernel<<<768, 256, 0, stream>>>(Wq, wq_b, W1, w1_b, W2, w2_b,
      Wk, wkt_b, Wv, wv_b, Wo, wo_b);
  // 2. Qb = bf16((node @ Wq^T + bq) / sqrt(32))  — f32 A, cvt in staging
  gemm_qb<<<dim3(NROWS/64, 2), 256, 0, stream>>>(node, wq_b, bq, Qb,
      0.17677669529663687f);
  // 3. qk[n][h*256+e] (per-head K=32)
  gemm_qk<<<dim3(NROWS/128, 2, 8), 256, 0, stream>>>(Qb, wkt_b, qk);
  // 4. fused attention -> pbar (masked rows never fetched)
  attn2_kernel<<<NROWS/4, 256, 0, stream>>>(neigh, maskp, qk, pbar);
  // 5. vbar[n][h*32+c] = pbar[n][h-slice] @ Wv_row + bv   (per-head K=256)
  gemm_vbar<<<dim3(NROWS/128, 8), 256, 0, stream>>>(pbar, wv_b, bvp, vbar);
  // 6. xb = LN1(node + vbar @ Wo^T + bo)   (K=256, 64-row tile)
  gemm_ln<0><<<NROWS/64, 256, 0, stream>>>(vbar, wo_b, bo, node, g1, be1, xb, 256);
  // 7. h = relu(xb @ W1^T + b1)
  gemm64<0><<<dim3(NROWS/64, 8), 256, 0, stream>>>(xb, w1_b, b1, hbuf, 1024, 256, 1.f);
  // 8. out = LN2(xb + h @ W2^T + b2)   (64-row tile: W2 re-read halved)
  gemm_ln<1><<<NROWS/64, 256, 0, stream>>>(hbuf, w2_b, b2, xb, g2, be2, (float*)d_out, 1024);
}

// Round 15
// 212.455 us; speedup vs baseline: 1.0205x; 1.0205x over previous
//
#include <hip/hip_runtime.h>

#define NM 32
#define ND 256
#define NH 8
#define NFF 1024
#define NROWS 16384

typedef __attribute__((ext_vector_type(8))) short short8;
typedef __attribute__((ext_vector_type(4))) float floatx4;

__device__ __forceinline__ unsigned short f2bf(float f){
  unsigned u = __float_as_uint(f);
  u += 0x7fffu + ((u >> 16) & 1u);
  return (unsigned short)(u >> 16);
}
__device__ __forceinline__ float bf2f(unsigned short s){
  return __uint_as_float(((unsigned)s) << 16);
}

// ================= mega-prep: all weight conversions in ONE dispatch =========
// [0,4096): node cvt   [4096,4160): Wq   [4160,4416): W1   [4416,4672): W2
// [4672,4736): Wk transpose+cvt   [4736,4800): Wv cvt   [4800,4864): Wo cvt
__global__ __launch_bounds__(256) void prep_kernel(
    const float* __restrict__ node, unsigned short* __restrict__ node_b,
    const float* __restrict__ Wq, unsigned short* __restrict__ wq_b,
    const float* __restrict__ W1, unsigned short* __restrict__ w1_b,
    const float* __restrict__ W2, unsigned short* __restrict__ w2_b,
    const float* __restrict__ Wk, unsigned short* __restrict__ wkt_b,
    const float* __restrict__ Wv, unsigned short* __restrict__ wv_b,
    const float* __restrict__ Wo, unsigned short* __restrict__ wo_b){
  __shared__ float T[32][33];
  const int b = blockIdx.x, tid = threadIdx.x;
  if (b < 4672 || b >= 4736){
    const float* src; unsigned short* dst; int i;
    if      (b < 4096){ src = node; dst = node_b; i = b*256 + tid; }
    else if (b < 4160){ src = Wq;   dst = wq_b;   i = (b-4096)*256 + tid; }
    else if (b < 4416){ src = W1;   dst = w1_b;   i = (b-4160)*256 + tid; }
    else if (b < 4672){ src = W2;   dst = w2_b;   i = (b-4416)*256 + tid; }
    else if (b < 4800){ src = Wv;   dst = wv_b;   i = (b-4736)*256 + tid; }
    else              { src = Wo;   dst = wo_b;   i = (b-4800)*256 + tid; }
    const float4 v = ((const float4*)src)[i];
    ushort4 o; o.x=f2bf(v.x); o.y=f2bf(v.y); o.z=f2bf(v.z); o.w=f2bf(v.w);
    ((ushort4*)dst)[i] = o;
  } else {
    const int bb = b - 4672, ti = bb >> 3, tj = bb & 7;
    {
      const int r = tid >> 3, c4 = (tid & 7) * 4;
      const float4 v = *(const float4*)&Wk[(ti*32 + r)*256 + tj*32 + c4];
      T[r][c4+0]=v.x; T[r][c4+1]=v.y; T[r][c4+2]=v.z; T[r][c4+3]=v.w;
    }
    __syncthreads();
    {
      const int cc = tid >> 3, r4 = (tid & 7) * 4;
      ushort4 o;
      o.x=f2bf(T[r4+0][cc]); o.y=f2bf(T[r4+1][cc]);
      o.z=f2bf(T[r4+2][cc]); o.w=f2bf(T[r4+3][cc]);
      *(ushort4*)&wkt_b[(tj*32 + cc)*256 + ti*32 + r4] = o;
    }
  }
}

// ================ gemm64: 64x128 tile, 4 waves (2x2 of 32x64) ===============
// EPI 0: relu(acc+bias)->bf16 ; EPI 1: (acc+bias)*scale->bf16
template<int EPI>
__global__ __launch_bounds__(256) void gemm64(const unsigned short* __restrict__ A,
    const unsigned short* __restrict__ W, const float* __restrict__ bias,
    unsigned short* __restrict__ out, int Nc, int K, float scale){
  __shared__ unsigned short As[64][40];
  __shared__ unsigned short Bs[128][40];
  const int tid = threadIdx.x;
  const int wid = tid >> 6, lane = tid & 63, ln = lane & 15, kh = lane >> 4;
  const int wr = (wid >> 1) * 32, wc = (wid & 1) * 64;
  const int row0 = blockIdx.x * 64, col0 = blockIdx.y * 128;
  const int ar = tid >> 2, ac = (tid & 3) * 8;
  const int br = tid >> 1, bc = (tid & 1) * 16;
  floatx4 acc[2][4] = {};
  for (int k0 = 0; k0 < K; k0 += 32){
    __syncthreads();
    *(short8*)&As[ar][ac]   = *(const short8*)&A[(size_t)(row0+ar)*K + k0 + ac];
    *(short8*)&Bs[br][bc]   = *(const short8*)&W[(size_t)(col0+br)*K + k0 + bc];
    *(short8*)&Bs[br][bc+8] = *(const short8*)&W[(size_t)(col0+br)*K + k0 + bc + 8];
    __syncthreads();
    short8 af[2], bf[4];
    #pragma unroll
    for (int t = 0; t < 2; ++t) af[t] = *(const short8*)&As[wr + t*16 + ln][kh*8];
    #pragma unroll
    for (int t = 0; t < 4; ++t) bf[t] = *(const short8*)&Bs[wc + t*16 + ln][kh*8];
    #pragma unroll
    for (int mt = 0; mt < 2; ++mt)
      #pragma unroll
      for (int nt = 0; nt < 4; ++nt)
        acc[mt][nt] = __builtin_amdgcn_mfma_f32_16x16x32_bf16(af[mt], bf[nt], acc[mt][nt], 0, 0, 0);
  }
  #pragma unroll
  for (int mt = 0; mt < 2; ++mt){
    #pragma unroll
    for (int nt = 0; nt < 4; ++nt){
      const int gc = col0 + wc + nt*16 + ln;
      const float bs = bias[gc];
      #pragma unroll
      for (int r = 0; r < 4; ++r){
        const int gr = row0 + wr + mt*16 + kh*4 + r;
        const float v = acc[mt][nt][r] + bs;
        if (EPI == 0) out[(size_t)gr*Nc + gc] = f2bf(fmaxf(v, 0.f));
        else          out[(size_t)gr*Nc + gc] = f2bf(v * scale);
      }
    }
  }
}

// ---------------- qk GEMM (per head, K=32): qk[n][h*256+e] -------------------
__global__ __launch_bounds__(256) void gemm_qk(const unsigned short* __restrict__ A,
    const unsigned short* __restrict__ Wkt, unsigned short* __restrict__ out){
  __shared__ unsigned short As[128][40];
  __shared__ unsigned short Bs[128][40];
  const int tid = threadIdx.x;
  const int wid = tid >> 6, lane = tid & 63, ln = lane & 15, kh = lane >> 4;
  const int wr = (wid >> 1) * 64, wc = (wid & 1) * 64;
  const int row0 = blockIdx.x * 128, col0 = blockIdx.y * 128, h = blockIdx.z;
  #pragma unroll
  for (int it = 0; it < 2; ++it){
    const int flat = it*256 + tid;
    const int r = flat >> 2, c = flat & 3;
    *(short8*)&As[r][c*8] = *(const short8*)&A[(size_t)(row0+r)*256 + h*32 + c*8];
    *(short8*)&Bs[r][c*8] = *(const short8*)&Wkt[(size_t)(col0+r)*256 + h*32 + c*8];
  }
  __syncthreads();
  short8 af[4], bf[4];
  #pragma unroll
  for (int t = 0; t < 4; ++t) af[t] = *(const short8*)&As[wr + t*16 + ln][kh*8];
  #pragma unroll
  for (int t = 0; t < 4; ++t) bf[t] = *(const short8*)&Bs[wc + t*16 + ln][kh*8];
  floatx4 acc[4][4] = {};
  #pragma unroll
  for (int mt = 0; mt < 4; ++mt)
    #pragma unroll
    for (int nt = 0; nt < 4; ++nt)
      acc[mt][nt] = __builtin_amdgcn_mfma_f32_16x16x32_bf16(af[mt], bf[nt], acc[mt][nt], 0, 0, 0);
  #pragma unroll
  for (int mt = 0; mt < 4; ++mt)
    #pragma unroll
    for (int nt = 0; nt < 4; ++nt)
      #pragma unroll
      for (int r = 0; r < 4; ++r)
        out[(size_t)(row0 + wr + mt*16 + kh*4 + r)*2048 + h*256 + col0 + wc + nt*16 + ln]
            = f2bf(acc[mt][nt][r]);
}

// ====== gemm_vbar: vbar[n][h*32+c] = pbar[n][h-slice]@Wv_row + bv ===========
// grid (NROWS/128, 8 heads); 4 waves x (32 rows x 32 cols); K=256
__global__ __launch_bounds__(256) void gemm_vbar(const unsigned short* __restrict__ A,
    const unsigned short* __restrict__ Wv, const float* __restrict__ bv,
    unsigned short* __restrict__ out){
  __shared__ unsigned short As[128][40];
  __shared__ unsigned short Bs[32][40];
  const int tid = threadIdx.x, wid = tid >> 6, lane = tid & 63;
  const int ln = lane & 15, kh = lane >> 4;
  const int row0 = blockIdx.x * 128, h = blockIdx.y;
  floatx4 acc[2][2] = {};
  for (int k0 = 0; k0 < 256; k0 += 32){
    __syncthreads();
    {
      const int r = tid >> 2, c = (tid & 3) * 8;
      *(short8*)&As[r][c]    = *(const short8*)&A[(size_t)(row0+r)*2048 + h*256 + k0 + c];
      *(short8*)&As[r+64][c] = *(const short8*)&A[(size_t)(row0+r+64)*2048 + h*256 + k0 + c];
    }
    if (tid < 128){
      const int r = tid >> 2, c = (tid & 3) * 8;
      *(short8*)&Bs[r][c] = *(const short8*)&Wv[(size_t)(h*32+r)*256 + k0 + c];
    }
    __syncthreads();
    short8 af[2], bf[2];
    #pragma unroll
    for (int t = 0; t < 2; ++t) af[t] = *(const short8*)&As[wid*32 + t*16 + ln][kh*8];
    #pragma unroll
    for (int t = 0; t < 2; ++t) bf[t] = *(const short8*)&Bs[t*16 + ln][kh*8];
    #pragma unroll
    for (int mt = 0; mt < 2; ++mt)
      #pragma unroll
      for (int nt = 0; nt < 2; ++nt)
        acc[mt][nt] = __builtin_amdgcn_mfma_f32_16x16x32_bf16(af[mt], bf[nt], acc[mt][nt], 0, 0, 0);
  }
  #pragma unroll
  for (int mt = 0; mt < 2; ++mt)
    #pragma unroll
    for (int nt = 0; nt < 2; ++nt){
      const int gc = h*32 + nt*16 + ln;
      const float bs = bv[gc];
      #pragma unroll
      for (int r = 0; r < 4; ++r){
        const int gr = row0 + wid*32 + mt*16 + kh*4 + r;
        out[(size_t)gr*256 + gc] = f2bf(acc[mt][nt][r] + bs);
      }
    }
}

// ===== gemm_ln: 32x256 full-width tile + fused residual + LayerNorm =========
// VAR 0: resid f32, out bf16 ; VAR 1: resid bf16, out f32
template<int VAR>
__global__ __launch_bounds__(256) void gemm_ln(const unsigned short* __restrict__ A,
    const unsigned short* __restrict__ W, const float* __restrict__ bias,
    const void* __restrict__ resid, const float* __restrict__ g,
    const float* __restrict__ be, void* __restrict__ out, int K){
  __shared__ unsigned short As[32][40];
  __shared__ unsigned short Bs[256][40];
  __shared__ float red[32][4][2];
  const int tid = threadIdx.x, wid = tid >> 6, lane = tid & 63;
  const int ln = lane & 15, kh = lane >> 4;
  const int row0 = blockIdx.x * 32;
  floatx4 acc[2][4] = {};
  for (int k0 = 0; k0 < K; k0 += 32){
    __syncthreads();
    if (tid < 128){
      const int r = tid >> 2, c = (tid & 3) * 8;
      *(short8*)&As[r][c] = *(const short8*)&A[(size_t)(row0+r)*K + k0 + c];
    }
    {
      const int rb = tid >> 2, c = (tid & 3) * 8;
      #pragma unroll
      for (int i = 0; i < 4; ++i)
        *(short8*)&Bs[rb + i*64][c] = *(const short8*)&W[(size_t)(rb + i*64)*K + k0 + c];
    }
    __syncthreads();
    short8 af[2], bf[4];
    #pragma unroll
    for (int t = 0; t < 2; ++t) af[t] = *(const short8*)&As[t*16 + ln][kh*8];
    #pragma unroll
    for (int t = 0; t < 4; ++t) bf[t] = *(const short8*)&Bs[wid*64 + t*16 + ln][kh*8];
    #pragma unroll
    for (int mt = 0; mt < 2; ++mt)
      #pragma unroll
      for (int nt = 0; nt < 4; ++nt)
        acc[mt][nt] = __builtin_amdgcn_mfma_f32_16x16x32_bf16(af[mt], bf[nt], acc[mt][nt], 0, 0, 0);
  }
  #pragma unroll
  for (int mt = 0; mt < 2; ++mt)
    #pragma unroll
    for (int nt = 0; nt < 4; ++nt){
      const int col = wid*64 + nt*16 + ln;
      const float bs = bias[col];
      #pragma unroll
      for (int r = 0; r < 4; ++r){
        const size_t idx = (size_t)(row0 + mt*16 + kh*4 + r)*256 + col;
        const float rv = (VAR == 0) ? ((const float*)resid)[idx]
                                    : bf2f(((const unsigned short*)resid)[idx]);
        acc[mt][nt][r] += bs + rv;
      }
    }
  #pragma unroll
  for (int mt = 0; mt < 2; ++mt)
    #pragma unroll
    for (int r = 0; r < 4; ++r){
      float s = 0.f, q = 0.f;
      #pragma unroll
      for (int nt = 0; nt < 4; ++nt){ const float v = acc[mt][nt][r]; s += v; q += v*v; }
      #pragma unroll
      for (int off = 8; off; off >>= 1){
        s += __shfl_xor(s, off, 16);
        q += __shfl_xor(q, off, 16);
      }
      if (ln == 0){
        red[mt*16 + kh*4 + r][wid][0] = s;
        red[mt*16 + kh*4 + r][wid][1] = q;
      }
    }
  __syncthreads();
  float ge[4], bee[4];
  #pragma unroll
  for (int nt = 0; nt < 4; ++nt){
    const int col = wid*64 + nt*16 + ln;
    ge[nt] = g[col]; bee[nt] = be[col];
  }
  #pragma unroll
  for (int mt = 0; mt < 2; ++mt)
    #pragma unroll
    for (int r = 0; r < 4; ++r){
      const int rl = mt*16 + kh*4 + r;
      const float sum = red[rl][0][0] + red[rl][1][0] + red[rl][2][0] + red[rl][3][0];
      const float sq  = red[rl][0][1] + red[rl][1][1] + red[rl][2][1] + red[rl][3][1];
      const float mu = sum * (1.f/256.f);
      const float rs = rsqrtf(sq * (1.f/256.f) - mu*mu + 1e-5f);
      const size_t rowb = (size_t)(row0 + rl) * 256;
      #pragma unroll
      for (int nt = 0; nt < 4; ++nt){
        const int col = wid*64 + nt*16 + ln;
        const float o = (acc[mt][nt][r] - mu) * rs * ge[nt] + bee[nt];
        if (VAR == 0) ((unsigned short*)out)[rowb + col] = f2bf(o);
        else          ((float*)out)[rowb + col] = o;
      }
    }
}

// ---------------- fused attention: 1 wave = 1 node, no barriers ----------------
// Masked neighbors (P == exactly 0 after softmax) are never loaded from HBM.
__global__ __launch_bounds__(256) void attn2_kernel(const float* __restrict__ neigh,
    const int* __restrict__ mask, const unsigned short* __restrict__ qk,
    unsigned short* __restrict__ pbar){
  __shared__ unsigned short Xs[4][8192];
  __shared__ float Pl[4][32][8];
  __shared__ float Mf[4][32];
  const int tid = threadIdx.x;
  const int wid = tid >> 6, lane = tid & 63;
  const int ln = lane & 15, kh = lane >> 4;
  const size_t nid = (size_t)blockIdx.x * 4 + wid;
  unsigned short* X = Xs[wid];

  int mk = 0;
  if (lane < 32) mk = mask[nid*NM + lane];
  // row bitmap of unmasked neighbors (ballot: lane L<32 carries row L)
  const unsigned long long bal = __ballot(mk != 0);
  const unsigned rowmask = (unsigned)(bal & 0xffffffffull);
  const bool any = rowmask != 0;

  const float* xg = neigh + nid * (NM*ND);
  const float4 fz = {0.f, 0.f, 0.f, 0.f};
  float4 va[16], vb[16];
  #pragma unroll
  for (int i = 0; i < 16; ++i){
    const int f8 = i*64 + lane;
    const int row = f8 >> 5;                    // = 2i + (lane>>5)
    const bool keep = (!any) || ((rowmask >> row) & 1u);
    va[i] = fz; vb[i] = fz;
    if (keep){                                  // exec-masked loads: no HBM fetch when masked
      va[i] = *(const float4*)&xg[f8*8];
      vb[i] = *(const float4*)&xg[f8*8 + 4];
    }
  }
  short8 bfrag[8];
  const unsigned short* qkn = qk + nid*2048 + (size_t)(ln & 7)*256;
  #pragma unroll
  for (int kk = 0; kk < 8; ++kk) bfrag[kk] = *(const short8*)&qkn[kk*32 + kh*8];

  if (lane < 32) Mf[wid][lane] = mk ? 0.f : -1e9f;

  #pragma unroll
  for (int i = 0; i < 16; ++i){
    const int f8 = i*64 + lane;
    const int m = f8 >> 5, ec = f8 & 31;
    short8 v;
    v[0]=(short)f2bf(va[i].x); v[1]=(short)f2bf(va[i].y);
    v[2]=(short)f2bf(va[i].z); v[3]=(short)f2bf(va[i].w);
    v[4]=(short)f2bf(vb[i].x); v[5]=(short)f2bf(vb[i].y);
    v[6]=(short)f2bf(vb[i].z); v[7]=(short)f2bf(vb[i].w);
    *(short8*)&X[m*256 + ((ec ^ (m & 31)) << 3)] = v;
  }

  floatx4 acc0 = {}, acc1 = {};
  #pragma unroll
  for (int kk = 0; kk < 8; ++kk){
    const int slot = kk*4 + kh;
    const int m0 = ln, m1 = 16 + ln;
    const short8 a0 = *(const short8*)&X[m0*256 + ((slot ^ (m0 & 31)) << 3)];
    const short8 a1 = *(const short8*)&X[m1*256 + ((slot ^ (m1 & 31)) << 3)];
    acc0 = __builtin_amdgcn_mfma_f32_16x16x32_bf16(a0, bfrag[kk], acc0, 0, 0, 0);
    acc1 = __builtin_amdgcn_mfma_f32_16x16x32_bf16(a1, bfrag[kk], acc1, 0, 0, 0);
  }

  float p8[8]; float mx = -3.0e38f;
  #pragma unroll
  for (int r = 0; r < 4; ++r){
    const float s0 = acc0[r] + Mf[wid][kh*4 + r];
    const float s1 = acc1[r] + Mf[wid][16 + kh*4 + r];
    p8[r] = s0; p8[4+r] = s1;
    mx = fmaxf(mx, fmaxf(s0, s1));
  }
  mx = fmaxf(mx, __shfl_xor(mx, 16));
  mx = fmaxf(mx, __shfl_xor(mx, 32));
  float sum = 0.f;
  #pragma unroll
  for (int k = 0; k < 8; ++k){ p8[k] = __expf(p8[k] - mx); sum += p8[k]; }
  sum += __shfl_xor(sum, 16);
  sum += __shfl_xor(sum, 32);
  const float inv = 1.f / sum;
  if (ln < 8){
    #pragma unroll
    for (int r = 0; r < 4; ++r){
      Pl[wid][kh*4 + r][ln]      = p8[r]   * inv;
      Pl[wid][16 + kh*4 + r][ln] = p8[4+r] * inv;
    }
  }

  const int hh = lane >> 5, ec = lane & 31;
  float pb[4][8] = {};
  #pragma unroll 4
  for (int m = 0; m < 32; ++m){
    const short8 xv = *(const short8*)&X[m*256 + ((ec ^ (m & 31)) << 3)];
    const floatx4 pv = *(const floatx4*)&Pl[wid][m][hh*4];
    float xf[8];
    #pragma unroll
    for (int j = 0; j < 8; ++j) xf[j] = bf2f((unsigned short)xv[j]);
    #pragma unroll
    for (int r = 0; r < 4; ++r)
      #pragma unroll
      for (int j = 0; j < 8; ++j) pb[r][j] += pv[r] * xf[j];
  }
  unsigned short* dst = pbar + nid*2048 + ec*8;
  #pragma unroll
  for (int r = 0; r < 4; ++r){
    short8 o;
    #pragma unroll
    for (int j = 0; j < 8; ++j) o[j] = (short)f2bf(pb[r][j]);
    *(short8*)&dst[(hh*4 + r)*256] = o;
  }
}

// ---------------- launch ----------------
extern "C" void kernel_launch(void* const* d_in, const int* in_sizes, int n_in,
                              void* d_out, int out_size, void* d_ws, size_t ws_size,
                              hipStream_t stream){
  const float* node  = (const float*)d_in[0];
  const float* neigh = (const float*)d_in[1];
  const int*   maskp = (const int*)d_in[2];
  const float* Wq = (const float*)d_in[3];  const float* bq = (const float*)d_in[4];
  const float* Wk = (const float*)d_in[5];  /* bk dropped: softmax-invariant */
  const float* Wv = (const float*)d_in[7];  const float* bvp = (const float*)d_in[8];
  const float* Wo = (const float*)d_in[9];  const float* bo = (const float*)d_in[10];
  const float* g1 = (const float*)d_in[11]; const float* be1 = (const float*)d_in[12];
  const float* W1 = (const float*)d_in[13]; const float* b1 = (const float*)d_in[14];
  const float* W2 = (const float*)d_in[15]; const float* b2 = (const float*)d_in[16];
  const float* g2 = (const float*)d_in[17]; const float* be2 = (const float*)d_in[18];

  char* ws = (char*)d_ws;
  unsigned short* wq_b  = (unsigned short*)(ws);              // 128K
  unsigned short* w1_b  = (unsigned short*)(ws + 131072);     // 512K
  unsigned short* w2_b  = (unsigned short*)(ws + 655360);     // 512K
  unsigned short* wkt_b = (unsigned short*)(ws + 1179648);    // 128K
  unsigned short* wv_b  = (unsigned short*)(ws + 1310720);    // 128K
  unsigned short* wo_b  = (unsigned short*)(ws + 1441792);    // 128K

  const size_t MB = 1048576ull;
  char* big = ws + 4*MB;
  unsigned short* node_b = (unsigned short*)(big);            // 8M
  unsigned short* Qb     = (unsigned short*)(big + 8*MB);     // 8M
  unsigned short* xb     = (unsigned short*)(big + 16*MB);    // 8M
  unsigned short* qk     = (unsigned short*)(big + 24*MB);    // 64M
  unsigned short* pbar   = (unsigned short*)(big + 88*MB);    // 64M
  unsigned short* vbar   = (unsigned short*)(big + 152*MB);   // 8M
  unsigned short* hbuf   = (unsigned short*)(big + 160*MB);   // 32M
  const size_t need = 4*MB + 192*MB;
  if (ws_size < need) return;

  // 1. all prep in one dispatch
  prep_kernel<<<4864, 256, 0, stream>>>(node, node_b, Wq, wq_b, W1, w1_b, W2, w2_b,
      Wk, wkt_b, Wv, wv_b, Wo, wo_b);
  // 2. Qb = bf16((node @ Wq^T + bq) / sqrt(32))
  gemm64<1><<<dim3(NROWS/64, 2), 256, 0, stream>>>(node_b, wq_b, bq, Qb,
      256, 256, 0.17677669529663687f);
  // 3. qk[n][h*256+e] (per-head K=32)
  gemm_qk<<<dim3(NROWS/128, 2, 8), 256, 0, stream>>>(Qb, wkt_b, qk);
  // 4. fused attention -> pbar (masked rows never fetched)
  attn2_kernel<<<NROWS/4, 256, 0, stream>>>(neigh, maskp, qk, pbar);
  // 5. vbar[n][h*32+c] = pbar[n][h-slice] @ Wv_row + bv   (per-head K=256)
  gemm_vbar<<<dim3(NROWS/128, 8), 256, 0, stream>>>(pbar, wv_b, bvp, vbar);
  // 6. xb = LN1(node + vbar @ Wo^T + bo)   (K=256)
  gemm_ln<0><<<NROWS/32, 256, 0, stream>>>(vbar, wo_b, bo, node, g1, be1, xb, 256);
  // 7. h = relu(xb @ W1^T + b1)
  gemm64<0><<<dim3(NROWS/64, 8), 256, 0, stream>>>(xb, w1_b, b1, hbuf, 1024, 256, 1.f);
  // 8. out = LN2(xb + h @ W2^T + b2)
  gemm_ln<1><<<NROWS/32, 256, 0, stream>>>(hbuf, w2_b, b2, xb, g2, be2, (float*)d_out, 1024);
}